// Round 10
// baseline (58.400 us; speedup 1.0000x reference)
//
#include <hip/hip_runtime.h>

#define B_ 32
#define T_ 8192
#define F_ 256
#define H_ 128

typedef short bf16x8 __attribute__((ext_vector_type(8)));
typedef float f32x4  __attribute__((ext_vector_type(4)));

// Hardware packed f32->bf16 RNE conversion (1 VALU op for 2 values).
static __device__ __forceinline__ unsigned int pack_bf2(float lo, float hi) {
    unsigned int r;
    asm("v_cvt_pk_bf16_f32 %0, %1, %2" : "=v"(r) : "v"(lo), "v"(hi));
    return r;
}

// tanh(x) = 1 - 2/(e^{2x}+1) via v_exp_f32 (exp2). No clamp needed:
// e^{+inf}=inf -> rcp=0 -> 1; e^{-inf}=0 -> 1-2 = -1. |err| ~1e-6.
static __device__ __forceinline__ float fast_tanh(float x) {
    float e = __builtin_amdgcn_exp2f(x * 2.8853900817779268f);  // e^{2x}
    return 1.f - 2.f * __builtin_amdgcn_rcpf(e + 1.f);
}

// Round 10: (4 h-waves) x (16-row steps) with B-frag reuse.
// 1024 blocks x 256 threads (4 waves). Block -> (b = blk>>5, t0=(blk&31)*256).
// 16 steps of 16 rows, double-buffered LDS (2 x 8 KB), 1 lgkm-barrier/step.
// Wave wh owns h-columns [32wh, 32wh+32) = TWO 16-h ntiles; per step it does
// 8 ds_read_b128 (enc B-frags, k-slices) REUSED by 2 MFMAs each (A = W1
// frags for ntl=0,1) -> per-CU LDS-read traffic HALVED vs the 8-wave h-split
// (1 read fed 1 MFMA there). Smaller blocks (4-wave barriers) + 4 blocks/CU
// give inter-block phase diversity so read/VALU/stage bursts from different
// blocks overlap instead of CU-wide lockstep; setprio(1) around the MFMA
// cluster exploits that diversity (T5).
// Swapped-operand MFMA (round 9): D = W1^T * enc^T; A[row=c][k=8q+j] =
// W1[f=64q+8ks+j][32wh+16ntl+c]; B[k][col=c] = enc[t=st*16+c][f]; D row=4q+r
// -> h = 32wh+16ntl+4q+r, col=c -> t. V-dot over h: in-lane FMAs + 2 shfl.
// Barrier = raw s_barrier + lgkmcnt(0) ONLY (no vmcnt drain): prefetch loads
// stay in flight across it. Race: stage of step s+2 overwrites buf[s&1] only
// after barrier s+1, which follows all step-s reads. Safe.
// NOTE: no min-waves bound (round 5: forced VGPR<=128 spilled, 60->106 us).
__global__ __launch_bounds__(256) void attn_fused(const float* __restrict__ enc,
                                                  const float* __restrict__ dec,
                                                  const float* __restrict__ W1,
                                                  const float* __restrict__ W2,
                                                  const float* __restrict__ Vvec,
                                                  float* __restrict__ out) {
    __shared__ __align__(16) unsigned char tile_lds[2][16 * 512]; // 2 x 8 KB
    __shared__ float red[4][256];    // 4 KB: per-wave col partials
    __shared__ float w2dp[2][128];   // w2d partial sums
    __shared__ float w2dv[128];      // w2d[b][:]

    const int tid  = threadIdx.x;
    const int blk  = blockIdx.x;
    const int b    = blk >> 5;
    const int t0   = (blk & 31) << 8;
    const int wh   = tid >> 6;      // wave: h-slice [32wh, 32wh+32)
    const int lane = tid & 63;
    const int q    = lane >> 4;     // k-quarter; D: h-row-group
    const int c    = lane & 15;     // B/D: t-col; A: h-row

    const f32x4* src = (const f32x4*)(enc + ((size_t)b * T_ + t0) * F_);

    // ---- issue step-0 loads first: latency overlaps W1/w2d setup ----
    f32x4 x[4];
    #pragma unroll
    for (int i = 0; i < 4; ++i) x[i] = src[i * 256 + tid];

    // ---- W1 -> A-fragments in registers: 2 ntiles x 8 ks (64 VGPR) ----
    bf16x8 bw[2][8];
    #pragma unroll
    for (int ntl = 0; ntl < 2; ++ntl) {
        const int h = 32 * wh + 16 * ntl + c;
        #pragma unroll
        for (int ks = 0; ks < 8; ++ks) {
            const float* wp = W1 + (64 * q + 8 * ks) * H_ + h;
            union { bf16x8 v; unsigned int u[4]; } pk;
            #pragma unroll
            for (int jj = 0; jj < 4; ++jj)
                pk.u[jj] = pack_bf2(wp[(2 * jj) * H_], wp[(2 * jj + 1) * H_]);
            bw[ntl][ks] = pk.v;
        }
    }

    // ---- w2d[b][hh] = dec[b]@W2[:,hh], 2-way f-split (fp32 exact) ----
    {
        const int hh = tid & 127, p = tid >> 7;
        const float* dp  = dec + b * F_ + p * 128;     // uniform -> scalar loads
        const float* w2p = W2 + (p * 128) * H_ + hh;   // coalesced per f
        float s = 0.f;
        #pragma unroll 8
        for (int f = 0; f < 128; ++f) s += dp[f] * w2p[f * H_];
        w2dp[p][hh] = s;
    }
    __syncthreads();
    if (tid < 128) w2dv[tid] = w2dp[0][tid] + w2dp[1][tid];
    __syncthreads();

    // Per-lane epilogue constants for D rows h = 32wh + 16ntl + 4q + r
    float Vv[2][4], wd[2][4];
    #pragma unroll
    for (int ntl = 0; ntl < 2; ++ntl)
        #pragma unroll
        for (int r = 0; r < 4; ++r) {
            const int hr = 32 * wh + 16 * ntl + 4 * q + r;
            Vv[ntl][r] = Vvec[hr];
            wd[ntl][r] = w2dv[hr];
        }
    const int sw = c & 7;

    for (int st = 0; st < 16; ++st) {
        unsigned char* buf = tile_lds[st & 1];

        // ---- pack regs -> bf16 (cvt_pk) -> swizzled LDS (frees x) ----
        #pragma unroll
        for (int i = 0; i < 4; ++i) {
            const int flat4 = i * 256 + tid;   // 0..1023
            const int row   = flat4 >> 6;      // 0..15
            const int c4    = flat4 & 63;      // f32x4 chunk in row
            const int chunk = (c4 >> 1) ^ (row & 7);
            uint2 v;
            v.x = pack_bf2(x[i][0], x[i][1]);
            v.y = pack_bf2(x[i][2], x[i][3]);
            *(uint2*)(buf + row * 512 + chunk * 16 + (c4 & 1) * 8) = v;
        }

        // ---- issue next step's loads: stay in flight across barrier ----
        if (st < 15) {
            const f32x4* sp = src + (st + 1) * 1024;
            #pragma unroll
            for (int i = 0; i < 4; ++i) x[i] = sp[i * 256 + tid];
        }

        // LDS-writes visible; global loads NOT drained (lgkmcnt only).
        asm volatile("s_waitcnt lgkmcnt(0)\n\ts_barrier" ::: "memory");

        // ---- compute: 8 ds_reads, each feeding 2 MFMAs (ntl=0,1) ----
        __builtin_amdgcn_s_setprio(1);
        const unsigned char* rbase = buf + c * 512;
        f32x4 a0 = {0.f, 0.f, 0.f, 0.f};
        f32x4 a1 = {0.f, 0.f, 0.f, 0.f};
        #pragma unroll
        for (int ks = 0; ks < 8; ++ks) {
            bf16x8 be = *(const bf16x8*)(rbase + ((8 * q + ks) ^ sw) * 16);
            a0 = __builtin_amdgcn_mfma_f32_16x16x32_bf16(bw[0][ks], be, a0, 0, 0, 0);
            a1 = __builtin_amdgcn_mfma_f32_16x16x32_bf16(bw[1][ks], be, a1, 0, 0, 0);
        }
        __builtin_amdgcn_s_setprio(0);

        // ---- epilogue: 8 tanh, V-dot in-lane, 2-stage shfl over q ----
        float part = Vv[0][0] * fast_tanh(a0[0] + wd[0][0])
                   + Vv[0][1] * fast_tanh(a0[1] + wd[0][1])
                   + Vv[0][2] * fast_tanh(a0[2] + wd[0][2])
                   + Vv[0][3] * fast_tanh(a0[3] + wd[0][3])
                   + Vv[1][0] * fast_tanh(a1[0] + wd[1][0])
                   + Vv[1][1] * fast_tanh(a1[1] + wd[1][1])
                   + Vv[1][2] * fast_tanh(a1[2] + wd[1][2])
                   + Vv[1][3] * fast_tanh(a1[3] + wd[1][3]);
        part += __shfl_xor(part, 16, 64);
        part += __shfl_xor(part, 32, 64);
        if (lane < 16) red[wh][st * 16 + c] = part;
    }

    __syncthreads();
    // ---- combine 4 wave-partials for 256 cols, coalesced store ----
    {
        float s = red[0][tid] + red[1][tid] + red[2][tid] + red[3][tid];
        out[(size_t)b * T_ + t0 + tid] = s;
    }
}

extern "C" void kernel_launch(void* const* d_in, const int* in_sizes, int n_in,
                              void* d_out, int out_size, void* d_ws, size_t ws_size,
                              hipStream_t stream) {
    const float* enc = (const float*)d_in[0];
    const float* dec = (const float*)d_in[1];
    const float* W1  = (const float*)d_in[2];
    const float* W2  = (const float*)d_in[3];
    const float* V   = (const float*)d_in[4];
    float* out = (float*)d_out;

    attn_fused<<<1024, 256, 0, stream>>>(enc, dec, W1, W2, V, out);
}

// Round 11
// 55.194 us; speedup vs baseline: 1.0581x; 1.0581x over previous
//
#include <hip/hip_runtime.h>

#define B_ 32
#define T_ 8192
#define F_ 256
#define H_ 128

typedef short bf16x8 __attribute__((ext_vector_type(8)));
typedef float f32x4  __attribute__((ext_vector_type(4)));

// Hardware packed f32->bf16 RNE conversion (1 VALU op for 2 values).
static __device__ __forceinline__ unsigned int pack_bf2(float lo, float hi) {
    unsigned int r;
    asm("v_cvt_pk_bf16_f32 %0, %1, %2" : "=v"(r) : "v"(lo), "v"(hi));
    return r;
}

// tanh(x) = 1 - 2/(e^{2x}+1) via v_exp_f32 (exp2). No clamp needed:
// e^{+inf}=inf -> rcp=0 -> 1; e^{-inf}=0 -> 1-2 = -1. |err| ~1e-6.
static __device__ __forceinline__ float fast_tanh(float x) {
    float e = __builtin_amdgcn_exp2f(x * 2.8853900817779268f);  // e^{2x}
    return 1.f - 2.f * __builtin_amdgcn_rcpf(e + 1.f);
}

// Round 11: round-9 geometry + B-frag reuse via (4 h-slices x 2 row-halves).
// 512 blocks x 512 threads (8 waves). Block -> (b = blk>>4, t0=(blk&15)*512);
// 16 half-tiles of 32 rows, double-buffered LDS (2 x 16 KB), 1 barrier/ht.
// Wave w = (wh = w&3, wg = w>>2): owns h-columns [32wh, 32wh+32) (2 ntiles,
// W1 A-frags bw[2][8] in regs) and row-half wg (16 of the 32 staged rows).
// Per half-tile per wave: 8 ds_read_b128, each feeding TWO MFMAs (ntl=0,1)
// -> per-CU LDS-read traffic HALVED vs round 9 (1 read fed 1 MFMA there),
// while barrier cadence (16 events/512 rows), grid fit (2 blocks/CU exact),
// staging and swizzle are round-9-identical. Round 10 showed 16-row steps
// double barrier overhead (+10 us) — avoided here.
// VGPR diet vs round 10: depth-1 prefetch (round 8: depth-2 null), w2d bias
// folded into the MFMA accumulator init (C-in = wd), no setprio. ~120 VGPR.
// Swapped-operand MFMA (round 9): D = W1^T * enc^T; D row=4q+r ->
// h = 32wh+16ntl+4q+r, col=c -> t = ht*32 + wg*16 + c. V-dot over h:
// in-lane FMAs + 2 shfl (xor 16, 32).
// Barrier = raw s_barrier + lgkmcnt(0) ONLY (no vmcnt drain): prefetch loads
// stay in flight. Race: STAGE(ht+2) overwrites buf[ht&1] only after
// BARRIER(ht+1), which every wave reaches only after COMPUTE(ht). Safe.
// NOTE: no min-waves bound (round 5: forced VGPR<=128 spilled, 60->106 us).
__global__ __launch_bounds__(512) void attn_fused(const float* __restrict__ enc,
                                                  const float* __restrict__ dec,
                                                  const float* __restrict__ W1,
                                                  const float* __restrict__ W2,
                                                  const float* __restrict__ Vvec,
                                                  float* __restrict__ out) {
    __shared__ __align__(16) unsigned char tile_lds[2][32 * 512]; // 2 x 16 KB
    __shared__ float red[4][512];    // 8 KB: per-h-slice col partials
    __shared__ float w2dp[4][128];   // w2d partial sums
    __shared__ float w2dv[128];      // w2d[b][:]

    const int tid  = threadIdx.x;
    const int blk  = blockIdx.x;
    const int b    = blk >> 4;
    const int t0   = (blk & 15) << 9;
    const int w    = tid >> 6;
    const int wh   = w & 3;         // h-slice [32wh, 32wh+32)
    const int wg   = w >> 2;        // row-half of each 32-row half-tile
    const int lane = tid & 63;
    const int q    = lane >> 4;     // k-quarter; D: h-row-group
    const int c    = lane & 15;     // B/D: t-col; A: h-row

    const f32x4* src = (const f32x4*)(enc + ((size_t)b * T_ + t0) * F_);

    // ---- issue half-tile 0 loads first: latency overlaps W1/w2d setup ----
    f32x4 x[4];
    #pragma unroll
    for (int i = 0; i < 4; ++i) x[i] = src[i * 512 + tid];

    // ---- W1 -> A-fragments in registers: 2 ntiles x 8 ks (64 VGPR) ----
    bf16x8 bw[2][8];
    #pragma unroll
    for (int ntl = 0; ntl < 2; ++ntl) {
        const int h = 32 * wh + 16 * ntl + c;
        #pragma unroll
        for (int ks = 0; ks < 8; ++ks) {
            const float* wp = W1 + (64 * q + 8 * ks) * H_ + h;
            union { bf16x8 v; unsigned int u[4]; } pk;
            #pragma unroll
            for (int jj = 0; jj < 4; ++jj)
                pk.u[jj] = pack_bf2(wp[(2 * jj) * H_], wp[(2 * jj + 1) * H_]);
            bw[ntl][ks] = pk.v;
        }
    }

    // ---- w2d[b][hh] = dec[b]@W2[:,hh], 4-way f-split (fp32 exact) ----
    {
        const int hh = tid & 127, p = tid >> 7;
        const float* dp  = dec + b * F_ + p * 64;      // uniform -> scalar loads
        const float* w2p = W2 + (p * 64) * H_ + hh;    // coalesced per f
        float s = 0.f;
        #pragma unroll 8
        for (int f = 0; f < 64; ++f) s += dp[f] * w2p[f * H_];
        w2dp[p][hh] = s;
    }
    __syncthreads();
    if (tid < 128)
        w2dv[tid] = w2dp[0][tid] + w2dp[1][tid] + w2dp[2][tid] + w2dp[3][tid];
    __syncthreads();

    // Per-lane epilogue constants for D rows h = 32wh + 16ntl + 4q + r.
    // wd is consumed as the MFMA accumulator INIT (C-in), saving 8 adds/step.
    f32x4 wd0, wd1;
    float Vv[2][4];
    #pragma unroll
    for (int r = 0; r < 4; ++r) {
        const int h0 = 32 * wh + 4 * q + r;
        wd0[r] = w2dv[h0];
        wd1[r] = w2dv[h0 + 16];
        Vv[0][r] = Vvec[h0];
        Vv[1][r] = Vvec[h0 + 16];
    }
    const int sw = c & 7;

    for (int ht = 0; ht < 16; ++ht) {
        unsigned char* buf = tile_lds[ht & 1];

        // ---- pack regs -> bf16 (cvt_pk) -> swizzled LDS (frees x) ----
        #pragma unroll
        for (int i = 0; i < 4; ++i) {
            const int flat4 = i * 512 + tid;   // 0..2047
            const int row   = flat4 >> 6;      // 0..31
            const int c4    = flat4 & 63;      // f32x4 chunk in row
            const int chunk = (c4 >> 1) ^ (row & 7);
            uint2 v;
            v.x = pack_bf2(x[i][0], x[i][1]);
            v.y = pack_bf2(x[i][2], x[i][3]);
            *(uint2*)(buf + row * 512 + chunk * 16 + (c4 & 1) * 8) = v;
        }

        // ---- issue next half-tile's loads: stay in flight across barrier ----
        if (ht < 15) {
            const f32x4* sp = src + (ht + 1) * 2048;
            #pragma unroll
            for (int i = 0; i < 4; ++i) x[i] = sp[i * 512 + tid];
        }

        // LDS-writes visible; global loads NOT drained (lgkmcnt only).
        asm volatile("s_waitcnt lgkmcnt(0)\n\ts_barrier" ::: "memory");

        // ---- compute row-half wg: 8 ds_reads, each feeding 2 MFMAs ----
        const unsigned char* rbase = buf + (wg * 16 + c) * 512;
        f32x4 a0 = wd0;          // accumulator pre-loaded with W2*dec bias
        f32x4 a1 = wd1;
        #pragma unroll
        for (int ks = 0; ks < 8; ++ks) {
            bf16x8 be = *(const bf16x8*)(rbase + ((8 * q + ks) ^ sw) * 16);
            a0 = __builtin_amdgcn_mfma_f32_16x16x32_bf16(bw[0][ks], be, a0, 0, 0, 0);
            a1 = __builtin_amdgcn_mfma_f32_16x16x32_bf16(bw[1][ks], be, a1, 0, 0, 0);
        }

        // ---- epilogue: 8 tanh, V-dot in-lane, 2-stage shfl over q ----
        float part = Vv[0][0] * fast_tanh(a0[0])
                   + Vv[0][1] * fast_tanh(a0[1])
                   + Vv[0][2] * fast_tanh(a0[2])
                   + Vv[0][3] * fast_tanh(a0[3])
                   + Vv[1][0] * fast_tanh(a1[0])
                   + Vv[1][1] * fast_tanh(a1[1])
                   + Vv[1][2] * fast_tanh(a1[2])
                   + Vv[1][3] * fast_tanh(a1[3]);
        part += __shfl_xor(part, 16, 64);
        part += __shfl_xor(part, 32, 64);
        if (lane < 16) red[wh][ht * 32 + wg * 16 + c] = part;
    }

    __syncthreads();
    // ---- combine 4 h-slice partials for all 512 rows, coalesced store ----
    {
        float s = red[0][tid] + red[1][tid] + red[2][tid] + red[3][tid];
        out[(size_t)b * T_ + t0 + tid] = s;
    }
}

extern "C" void kernel_launch(void* const* d_in, const int* in_sizes, int n_in,
                              void* d_out, int out_size, void* d_ws, size_t ws_size,
                              hipStream_t stream) {
    const float* enc = (const float*)d_in[0];
    const float* dec = (const float*)d_in[1];
    const float* W1  = (const float*)d_in[2];
    const float* W2  = (const float*)d_in[3];
    const float* V   = (const float*)d_in[4];
    float* out = (float*)d_out;

    attn_fused<<<512, 512, 0, stream>>>(enc, dec, W1, W2, V, out);
}

// Round 12
// 51.995 us; speedup vs baseline: 1.1232x; 1.0615x over previous
//
#include <hip/hip_runtime.h>

#define B_ 32
#define T_ 8192
#define F_ 256
#define H_ 128

typedef short bf16x8 __attribute__((ext_vector_type(8)));
typedef float f32x4  __attribute__((ext_vector_type(4)));

// Hardware packed f32->bf16 RNE conversion (1 VALU op for 2 values).
static __device__ __forceinline__ unsigned int pack_bf2(float lo, float hi) {
    unsigned int r;
    asm("v_cvt_pk_bf16_f32 %0, %1, %2" : "=v"(r) : "v"(lo), "v"(hi));
    return r;
}

// tanh(x) = 1 - 2/(e^{2x}+1) via v_exp_f32 (exp2). No clamp needed:
// e^{+inf}=inf -> rcp=0 -> 1; e^{-inf}=0 -> 1-2 = -1. |err| ~1e-6.
static __device__ __forceinline__ float fast_tanh(float x) {
    float e = __builtin_amdgcn_exp2f(x * 2.8853900817779268f);  // e^{2x}
    return 1.f - 2.f * __builtin_amdgcn_rcpf(e + 1.f);
}

// Round 12: R9 structure with 64-row half-tiles -> HALF the barrier events.
// 512 blocks x 512 threads (8 waves). Block -> (b = blk>>4, t0=(blk&15)*512);
// 8 half-tiles of 64 rows, double-buffered LDS (2 x 32 KB), 1 barrier/ht.
// Wave w owns ntile w (h-cols [16w,16w+16)), W1 A-frags bw[8] in regs (32
// VGPR, R9-identical). Depth-1 prefetch x[8] (32 VGPR): in-flight bytes per
// block = 64 KB = R9's depth-2 x 32-row, so the HBM feed pipeline is
// unchanged while sync points halve (R10 showed barrier-convoy cost scales
// with event count; R11 showed +32 VGPR for bw[2][8] costs more than LDS-
// read-halving gains — so bw stays [8], occupancy 16 waves/CU).
// LDS budget forces the cross-wave combine to be per-half-tile: COMPUTE(ht)
// writes red[ht&1][w][64]; after BARRIER(ht+1), tid<64 sums the 8 wave
// slots of red[ht&1] and stores 64 output rows. Race: red buffers alternate
// per ht; BARRIER(ht+1) (lgkmcnt(0)+s_barrier) orders all COMPUTE(ht)
// ds_writes before the combine reads; COMPUTE(ht+1) writes red[(ht+1)&1],
// a different buffer. tile race: STAGE(ht+2) overwrites buf[ht&1] only
// after BARRIER(ht+1), which every wave reaches after COMPUTE(ht). Safe.
// Swapped-operand MFMA (R9): D = W1^T * enc^T; D row=4q+r -> h=16w+4q+r,
// col=c -> t. V-dot over h: in-lane FMAs + 2 shfl (xor 16, 32).
// Barrier = raw s_barrier + lgkmcnt(0) ONLY (no vmcnt drain): prefetch
// loads stay in flight across it.
// NOTE: no min-waves bound (round 5: forced VGPR<=128 spilled, 60->106 us).
// LDS: 64 KB tile + 4 KB red + 2.5 KB w2d = 70.7 KB -> 2 blocks/CU exact.
__global__ __launch_bounds__(512) void attn_fused(const float* __restrict__ enc,
                                                  const float* __restrict__ dec,
                                                  const float* __restrict__ W1,
                                                  const float* __restrict__ W2,
                                                  const float* __restrict__ Vvec,
                                                  float* __restrict__ out) {
    __shared__ __align__(16) unsigned char tile_lds[2][64 * 512]; // 2 x 32 KB
    __shared__ float red[2][8][64];  // 4 KB: per-wave col partials, dbuf
    __shared__ float w2dp[4][128];   // w2d partial sums
    __shared__ float w2dv[128];      // w2d[b][:]

    const int tid  = threadIdx.x;
    const int blk  = blockIdx.x;
    const int b    = blk >> 4;
    const int t0   = (blk & 15) << 9;
    const int w    = tid >> 6;
    const int lane = tid & 63;
    const int q    = lane >> 4;     // k-quarter; D: h-row-group
    const int c    = lane & 15;     // B/D: t-col; A: h-row

    const f32x4* src = (const f32x4*)(enc + ((size_t)b * T_ + t0) * F_);

    // ---- issue half-tile 0 loads first: latency overlaps W1/w2d setup ----
    f32x4 x[8];
    #pragma unroll
    for (int i = 0; i < 8; ++i) x[i] = src[i * 512 + tid];

    // ---- W1 -> A-fragments in registers (wave w owns ntile w) ----
    const int h = 16 * w + c;
    bf16x8 bw[8];
    #pragma unroll
    for (int ks = 0; ks < 8; ++ks) {
        const float* wp = W1 + (64 * q + 8 * ks) * H_ + h;
        union { bf16x8 v; unsigned int u[4]; } pk;
        #pragma unroll
        for (int jj = 0; jj < 4; ++jj)
            pk.u[jj] = pack_bf2(wp[(2 * jj) * H_], wp[(2 * jj + 1) * H_]);
        bw[ks] = pk.v;
    }

    // ---- w2d[b][hh] = dec[b]@W2[:,hh], 4-way f-split (fp32 exact) ----
    {
        const int hh = tid & 127, p = tid >> 7;
        const float* dp  = dec + b * F_ + p * 64;      // uniform -> scalar loads
        const float* w2p = W2 + (p * 64) * H_ + hh;    // coalesced per f
        float s = 0.f;
        #pragma unroll 8
        for (int f = 0; f < 64; ++f) s += dp[f] * w2p[f * H_];
        w2dp[p][hh] = s;
    }
    __syncthreads();
    if (tid < 128)
        w2dv[tid] = w2dp[0][tid] + w2dp[1][tid] + w2dp[2][tid] + w2dp[3][tid];
    __syncthreads();

    // Per-lane epilogue constants for D rows h = 16w + 4q + r, r=0..3
    float Vv4[4], wd4[4];
    #pragma unroll
    for (int r = 0; r < 4; ++r) {
        const int hr = 16 * w + 4 * q + r;
        Vv4[r] = Vvec[hr];
        wd4[r] = w2dv[hr];
    }
    const int sw = c & 7;

    for (int ht = 0; ht < 8; ++ht) {
        unsigned char* buf = tile_lds[ht & 1];

        // ---- pack regs -> bf16 (cvt_pk) -> swizzled LDS (frees x) ----
        #pragma unroll
        for (int i = 0; i < 8; ++i) {
            const int flat4 = i * 512 + tid;   // 0..4095
            const int row   = flat4 >> 6;      // 0..63
            const int c4    = flat4 & 63;      // f32x4 chunk in row
            const int chunk = (c4 >> 1) ^ (row & 7);
            uint2 v;
            v.x = pack_bf2(x[i][0], x[i][1]);
            v.y = pack_bf2(x[i][2], x[i][3]);
            *(uint2*)(buf + row * 512 + chunk * 16 + (c4 & 1) * 8) = v;
        }

        // ---- issue next half-tile's loads: stay in flight across barrier ----
        if (ht < 7) {
            const f32x4* sp = src + (ht + 1) * 4096;
            #pragma unroll
            for (int i = 0; i < 8; ++i) x[i] = sp[i * 512 + tid];
        }

        // LDS-writes visible; global loads NOT drained (lgkmcnt only).
        asm volatile("s_waitcnt lgkmcnt(0)\n\ts_barrier" ::: "memory");

        // ---- combine previous half-tile's partials (dbuf'd red) ----
        if (ht > 0 && tid < 64) {
            const int prev = ht - 1;
            float s = 0.f;
            #pragma unroll
            for (int ww = 0; ww < 8; ++ww) s += red[prev & 1][ww][tid];
            out[(size_t)b * T_ + t0 + prev * 64 + tid] = s;
        }

        // ---- compute 4 row-groups of 16; K=256 via 8 MFMA steps each ----
        #pragma unroll
        for (int g = 0; g < 4; ++g) {
            const unsigned char* rbase = buf + (g * 16 + c) * 512;
            f32x4 acc = {0.f, 0.f, 0.f, 0.f};
            #pragma unroll
            for (int ks = 0; ks < 8; ++ks) {
                bf16x8 be = *(const bf16x8*)(rbase + ((8 * q + ks) ^ sw) * 16);
                acc = __builtin_amdgcn_mfma_f32_16x16x32_bf16(bw[ks], be, acc, 0, 0, 0);
            }
            float part = Vv4[0] * fast_tanh(acc[0] + wd4[0])
                       + Vv4[1] * fast_tanh(acc[1] + wd4[1])
                       + Vv4[2] * fast_tanh(acc[2] + wd4[2])
                       + Vv4[3] * fast_tanh(acc[3] + wd4[3]);
            part += __shfl_xor(part, 16, 64);
            part += __shfl_xor(part, 32, 64);
            if (lane < 16) red[ht & 1][w][g * 16 + c] = part;
        }
    }

    // ---- final combine for half-tile 7 ----
    asm volatile("s_waitcnt lgkmcnt(0)\n\ts_barrier" ::: "memory");
    if (tid < 64) {
        float s = 0.f;
        #pragma unroll
        for (int ww = 0; ww < 8; ++ww) s += red[1][ww][tid];
        out[(size_t)b * T_ + t0 + 7 * 64 + tid] = s;
    }
}

extern "C" void kernel_launch(void* const* d_in, const int* in_sizes, int n_in,
                              void* d_out, int out_size, void* d_ws, size_t ws_size,
                              hipStream_t stream) {
    const float* enc = (const float*)d_in[0];
    const float* dec = (const float*)d_in[1];
    const float* W1  = (const float*)d_in[2];
    const float* W2  = (const float*)d_in[3];
    const float* V   = (const float*)d_in[4];
    float* out = (float*)d_out;

    attn_fused<<<512, 512, 0, stream>>>(enc, dec, W1, W2, V, out);
}

// Round 13
// 51.411 us; speedup vs baseline: 1.1359x; 1.0114x over previous
//
#include <hip/hip_runtime.h>

#define B_ 32
#define T_ 8192
#define F_ 256
#define H_ 128

typedef short bf16x8 __attribute__((ext_vector_type(8)));
typedef float f32x4  __attribute__((ext_vector_type(4)));

// Hardware packed f32->bf16 RNE conversion (1 VALU op for 2 values).
static __device__ __forceinline__ unsigned int pack_bf2(float lo, float hi) {
    unsigned int r;
    asm("v_cvt_pk_bf16_f32 %0, %1, %2" : "=v"(r) : "v"(lo), "v"(hi));
    return r;
}

// tanh(x) = 1 - 2/(e^{2x}+1) via v_exp_f32 (exp2). No clamp needed:
// e^{+inf}=inf -> rcp=0 -> 1; e^{-inf}=0 -> 1-2 = -1. |err| ~1e-6.
static __device__ __forceinline__ float fast_tanh(float x) {
    float e = __builtin_amdgcn_exp2f(x * 2.8853900817779268f);  // e^{2x}
    return 1.f - 2.f * __builtin_amdgcn_rcpf(e + 1.f);
}

// Round 13 = Round 9 (best, 49.3 us) + NONTEMPORAL encoder loads.
// The encoder is read-once-per-replay (268 MB, L3 thrashed by harness fills
// between replays) — allocating it into L2/L3 costs eviction/fill BW with
// zero reuse benefit. nt-flagged global_load_dwordx4 skips cache allocation.
// Single-variable A/B vs R9; everything else byte-identical.
//
// R9 structure: 512 blocks x 512 threads (8 waves), b=blk>>4, t0=(blk&15)*512,
// 16 half-tiles of 32 rows, dbuf LDS (2 x 16 KB), 1 lgkm-only barrier/ht,
// depth-2 register prefetch xa/xb (statically indexed), swapped-operand MFMA
// (D = W1^T * enc^T: A = W1 frags in regs, B = enc tile from LDS; V-dot over
// h = in-lane FMAs + 2 shfl_xor). Race analysis in R9 comments held (passed).
// NOTE: no min-waves bound (round 5: forced VGPR<=128 spilled, 60->106 us).
__global__ __launch_bounds__(512) void attn_fused(const float* __restrict__ enc,
                                                  const float* __restrict__ dec,
                                                  const float* __restrict__ W1,
                                                  const float* __restrict__ W2,
                                                  const float* __restrict__ Vvec,
                                                  float* __restrict__ out) {
    __shared__ __align__(16) unsigned char tile_lds[2][32 * 512]; // 2 x 16 KB
    __shared__ float red[8][512];    // 16 KB: per-wave row partials
    __shared__ float w2dp[4][128];   // w2d partial sums
    __shared__ float w2dv[128];      // w2d[b][:]

    const int tid  = threadIdx.x;
    const int blk  = blockIdx.x;
    const int b    = blk >> 4;
    const int t0   = (blk & 15) << 9;
    const int w    = tid >> 6;
    const int lane = tid & 63;
    const int q    = lane >> 4;     // k-quarter; D: h-row-group
    const int c    = lane & 15;     // B: t-col; A: h-row

    const f32x4* src = (const f32x4*)(enc + ((size_t)b * T_ + t0) * F_);

    // ---- issue half-tiles 0 and 1 loads first (nt): latency overlaps setup ----
    f32x4 xa[4], xb[4];
    #pragma unroll
    for (int i = 0; i < 4; ++i) xa[i] = __builtin_nontemporal_load(&src[i * 512 + tid]);
    #pragma unroll
    for (int i = 0; i < 4; ++i) xb[i] = __builtin_nontemporal_load(&src[2048 + i * 512 + tid]);

    // ---- W1 -> fragments in registers (wave w owns h-ntile w) ----
    // bw[ks][j] = bf16(W1[64q + 8ks + j][16w + c]) — consumed as A-operand.
    const int h = 16 * w + c;
    bf16x8 bw[8];
    #pragma unroll
    for (int ks = 0; ks < 8; ++ks) {
        const float* wp = W1 + (64 * q + 8 * ks) * H_ + h;
        union { bf16x8 v; unsigned int u[4]; } pk;
        #pragma unroll
        for (int jj = 0; jj < 4; ++jj)
            pk.u[jj] = pack_bf2(wp[(2 * jj) * H_], wp[(2 * jj + 1) * H_]);
        bw[ks] = pk.v;
    }

    // ---- w2d[b][hh] = dec[b]@W2[:,hh], 4-way f-split (fp32 exact) ----
    {
        const int hh = tid & 127, p = tid >> 7;
        const float* dp  = dec + b * F_ + p * 64;      // uniform -> scalar loads
        const float* w2p = W2 + (p * 64) * H_ + hh;    // coalesced per f
        float s = 0.f;
        #pragma unroll 8
        for (int f = 0; f < 64; ++f) s += dp[f] * w2p[f * H_];
        w2dp[p][hh] = s;
    }
    __syncthreads();
    if (tid < 128)
        w2dv[tid] = w2dp[0][tid] + w2dp[1][tid] + w2dp[2][tid] + w2dp[3][tid];
    __syncthreads();

    // Per-lane epilogue constants for D rows h = 16w + 4q + r, r=0..3
    float Vv4[4], wd4[4];
    #pragma unroll
    for (int r = 0; r < 4; ++r) {
        const int hr = 16 * w + 4 * q + r;
        Vv4[r] = Vvec[hr];
        wd4[r] = w2dv[hr];
    }
    const int sw = c & 7;

// pack register half-tile X into LDS buffer BUF (cvt_pk + XOR swizzle)
#define STAGE(X, BUF)                                                        \
    {                                                                        \
        unsigned char* buf_ = (BUF);                                         \
        _Pragma("unroll")                                                    \
        for (int i = 0; i < 4; ++i) {                                        \
            const int flat4 = i * 512 + tid;                                 \
            const int row   = flat4 >> 6;                                    \
            const int c4    = flat4 & 63;                                    \
            const int chunk = (c4 >> 1) ^ (row & 7);                         \
            uint2 v;                                                         \
            v.x = pack_bf2((X)[i][0], (X)[i][1]);                            \
            v.y = pack_bf2((X)[i][2], (X)[i][3]);                            \
            *(uint2*)(buf_ + row * 512 + chunk * 16 + (c4 & 1) * 8) = v;     \
        }                                                                    \
    }

// issue nt global loads for half-tile HT into X (registers; no wait here)
#define ISSUE(X, HT)                                                         \
    {                                                                        \
        const f32x4* sp_ = src + (HT) * 2048;                                \
        _Pragma("unroll")                                                    \
        for (int i = 0; i < 4; ++i)                                          \
            (X)[i] = __builtin_nontemporal_load(&sp_[i * 512 + tid]);        \
    }

// compute half-tile HT from LDS buffer BUF (swapped-operand MFMA)
#define COMPUTE(BUF, HT)                                                     \
    {                                                                        \
        const unsigned char* bb_ = (BUF);                                    \
        _Pragma("unroll")                                                    \
        for (int g = 0; g < 2; ++g) {                                        \
            const unsigned char* rbase = bb_ + (g * 16 + c) * 512;           \
            f32x4 acc = {0.f, 0.f, 0.f, 0.f};                                \
            _Pragma("unroll")                                                \
            for (int ks = 0; ks < 8; ++ks) {                                 \
                bf16x8 be = *(const bf16x8*)(rbase + ((8 * q + ks) ^ sw) * 16);\
                acc = __builtin_amdgcn_mfma_f32_16x16x32_bf16(bw[ks], be, acc, 0, 0, 0);\
            }                                                                \
            float part = Vv4[0] * fast_tanh(acc[0] + wd4[0])                 \
                       + Vv4[1] * fast_tanh(acc[1] + wd4[1])                 \
                       + Vv4[2] * fast_tanh(acc[2] + wd4[2])                 \
                       + Vv4[3] * fast_tanh(acc[3] + wd4[3]);                \
            part += __shfl_xor(part, 16, 64);                                \
            part += __shfl_xor(part, 32, 64);                                \
            if (lane < 16)                                                   \
                red[w][(HT) * 32 + g * 16 + lane] = part;                    \
        }                                                                    \
    }

#define BARRIER() asm volatile("s_waitcnt lgkmcnt(0)\n\ts_barrier" ::: "memory")

    for (int it = 0; it < 8; ++it) {
        const int ht0 = 2 * it;
        // even half-tile: xa -> buf0
        STAGE(xa, tile_lds[0]);
        if (it < 7) ISSUE(xa, ht0 + 2);
        BARRIER();
        COMPUTE(tile_lds[0], ht0);
        // odd half-tile: xb -> buf1
        STAGE(xb, tile_lds[1]);
        if (it < 7) ISSUE(xb, ht0 + 3);
        BARRIER();
        COMPUTE(tile_lds[1], ht0 + 1);
    }

#undef STAGE
#undef ISSUE
#undef COMPUTE
#undef BARRIER

    __syncthreads();
    // ---- combine 8 wave-partials for all 512 rows, coalesced store ----
    float s = 0.f;
    #pragma unroll
    for (int ww = 0; ww < 8; ++ww) s += red[ww][tid];
    out[(size_t)b * T_ + t0 + tid] = s;
}

extern "C" void kernel_launch(void* const* d_in, const int* in_sizes, int n_in,
                              void* d_out, int out_size, void* d_ws, size_t ws_size,
                              hipStream_t stream) {
    const float* enc = (const float*)d_in[0];
    const float* dec = (const float*)d_in[1];
    const float* W1  = (const float*)d_in[2];
    const float* W2  = (const float*)d_in[3];
    const float* V   = (const float*)d_in[4];
    float* out = (float*)d_out;

    attn_fused<<<512, 512, 0, stream>>>(enc, dec, W1, W2, V, out);
}

// Round 14
// 48.666 us; speedup vs baseline: 1.2000x; 1.0564x over previous
//
#include <hip/hip_runtime.h>

#define B_ 32
#define T_ 8192
#define F_ 256
#define H_ 128

typedef short bf16x8 __attribute__((ext_vector_type(8)));
typedef float f32x4  __attribute__((ext_vector_type(4)));

// Hardware packed f32->bf16 RNE conversion (1 VALU op for 2 values).
static __device__ __forceinline__ unsigned int pack_bf2(float lo, float hi) {
    unsigned int r;
    asm("v_cvt_pk_bf16_f32 %0, %1, %2" : "=v"(r) : "v"(lo), "v"(hi));
    return r;
}

// tanh(x) = 1 - 2/(e^{2x}+1) via v_exp_f32 (exp2). No clamp needed:
// e^{+inf}=inf -> rcp=0 -> 1; e^{-inf}=0 -> 1-2 = -1. |err| ~1e-6.
static __device__ __forceinline__ float fast_tanh(float x) {
    float e = __builtin_amdgcn_exp2f(x * 2.8853900817779268f);  // e^{2x}
    return 1.f - 2.f * __builtin_amdgcn_rcpf(e + 1.f);
}

// FINAL = Round 9 champion (49.3 us), nt-load experiment reverted (R13: null).
// Session ledger: R2 166 (MFMA but divergent loads) -> R3 65 (coalesced LDS
// staging, W1 in regs) -> R4 61 (single barrier, deferred combine) -> R7 54
// (fused single kernel, lgkm-only barrier) -> R9 49.3 (swapped-operand MFMA:
// V-dot reduction moved in-lane, 8x fewer shfls). Dead ends: forced
// occupancy (R5: spill, 106), 16-row steps (R10: 58), bw[2][8] reuse (R11:
// 55), 64-row half-tiles (R12: 52), depth-2 prefetch (R8: null), nt (R13).
// At ~90% of achievable HBM read BW (268 MB / 6.3 TB/s = 43 us floor);
// MFMA ~5%, VALU ~30%, LDS ~30%, bank conflicts 0 — memory roofline.
//
// Structure: 512 blocks x 512 threads (8 waves), b=blk>>4, t0=(blk&15)*512,
// 16 half-tiles of 32 rows, dbuf LDS (2 x 16 KB), 1 lgkm-only barrier/ht
// (prefetch loads stay in flight across it — __syncthreads would drain
// vmcnt(0)), depth-2 register prefetch xa/xb (statically indexed, rule #20),
// swapped-operand MFMA: D = W1^T * enc^T, A = W1 frags in regs (contents
// equal the B-layout frags), B = enc tile from XOR-swizzled LDS; D row=4q+r
// -> h = 16w+4q+r, col=c -> t, so the V-dot over h is in-lane FMAs + 2
// shfl_xor (16, 32) instead of a 4-stage butterfly.
// Race: STAGE(ht+2) overwrites buf[ht&1] only after BARRIER(ht+1), which
// every wave reaches only after COMPUTE(ht)'s reads. Safe.
// NOTE: no min-waves bound (round 5: forced VGPR<=128 spilled, 60->106 us).
__global__ __launch_bounds__(512) void attn_fused(const float* __restrict__ enc,
                                                  const float* __restrict__ dec,
                                                  const float* __restrict__ W1,
                                                  const float* __restrict__ W2,
                                                  const float* __restrict__ Vvec,
                                                  float* __restrict__ out) {
    __shared__ __align__(16) unsigned char tile_lds[2][32 * 512]; // 2 x 16 KB
    __shared__ float red[8][512];    // 16 KB: per-wave row partials
    __shared__ float w2dp[4][128];   // w2d partial sums
    __shared__ float w2dv[128];      // w2d[b][:]

    const int tid  = threadIdx.x;
    const int blk  = blockIdx.x;
    const int b    = blk >> 4;
    const int t0   = (blk & 15) << 9;
    const int w    = tid >> 6;
    const int lane = tid & 63;
    const int q    = lane >> 4;     // k-quarter; D: h-row-group
    const int c    = lane & 15;     // B: t-col; A: h-row

    const f32x4* src = (const f32x4*)(enc + ((size_t)b * T_ + t0) * F_);

    // ---- issue half-tiles 0 and 1 loads first: latency overlaps setup ----
    f32x4 xa[4], xb[4];
    #pragma unroll
    for (int i = 0; i < 4; ++i) xa[i] = src[i * 512 + tid];
    #pragma unroll
    for (int i = 0; i < 4; ++i) xb[i] = src[2048 + i * 512 + tid];

    // ---- W1 -> fragments in registers (wave w owns h-ntile w) ----
    // bw[ks][j] = bf16(W1[64q + 8ks + j][16w + c]) — consumed as A-operand.
    const int h = 16 * w + c;
    bf16x8 bw[8];
    #pragma unroll
    for (int ks = 0; ks < 8; ++ks) {
        const float* wp = W1 + (64 * q + 8 * ks) * H_ + h;
        union { bf16x8 v; unsigned int u[4]; } pk;
        #pragma unroll
        for (int jj = 0; jj < 4; ++jj)
            pk.u[jj] = pack_bf2(wp[(2 * jj) * H_], wp[(2 * jj + 1) * H_]);
        bw[ks] = pk.v;
    }

    // ---- w2d[b][hh] = dec[b]@W2[:,hh], 4-way f-split (fp32 exact) ----
    {
        const int hh = tid & 127, p = tid >> 7;
        const float* dp  = dec + b * F_ + p * 64;      // uniform -> scalar loads
        const float* w2p = W2 + (p * 64) * H_ + hh;    // coalesced per f
        float s = 0.f;
        #pragma unroll 8
        for (int f = 0; f < 64; ++f) s += dp[f] * w2p[f * H_];
        w2dp[p][hh] = s;
    }
    __syncthreads();
    if (tid < 128)
        w2dv[tid] = w2dp[0][tid] + w2dp[1][tid] + w2dp[2][tid] + w2dp[3][tid];
    __syncthreads();

    // Per-lane epilogue constants for D rows h = 16w + 4q + r, r=0..3
    float Vv4[4], wd4[4];
    #pragma unroll
    for (int r = 0; r < 4; ++r) {
        const int hr = 16 * w + 4 * q + r;
        Vv4[r] = Vvec[hr];
        wd4[r] = w2dv[hr];
    }
    const int sw = c & 7;

// pack register half-tile X into LDS buffer BUF (cvt_pk + XOR swizzle)
#define STAGE(X, BUF)                                                        \
    {                                                                        \
        unsigned char* buf_ = (BUF);                                         \
        _Pragma("unroll")                                                    \
        for (int i = 0; i < 4; ++i) {                                        \
            const int flat4 = i * 512 + tid;                                 \
            const int row   = flat4 >> 6;                                    \
            const int c4    = flat4 & 63;                                    \
            const int chunk = (c4 >> 1) ^ (row & 7);                         \
            uint2 v;                                                         \
            v.x = pack_bf2((X)[i][0], (X)[i][1]);                            \
            v.y = pack_bf2((X)[i][2], (X)[i][3]);                            \
            *(uint2*)(buf_ + row * 512 + chunk * 16 + (c4 & 1) * 8) = v;     \
        }                                                                    \
    }

// issue global loads for half-tile HT into X (registers; no wait here)
#define ISSUE(X, HT)                                                         \
    {                                                                        \
        const f32x4* sp_ = src + (HT) * 2048;                                \
        _Pragma("unroll")                                                    \
        for (int i = 0; i < 4; ++i) (X)[i] = sp_[i * 512 + tid];             \
    }

// compute half-tile HT from LDS buffer BUF (swapped-operand MFMA)
#define COMPUTE(BUF, HT)                                                     \
    {                                                                        \
        const unsigned char* bb_ = (BUF);                                    \
        _Pragma("unroll")                                                    \
        for (int g = 0; g < 2; ++g) {                                        \
            const unsigned char* rbase = bb_ + (g * 16 + c) * 512;           \
            f32x4 acc = {0.f, 0.f, 0.f, 0.f};                                \
            _Pragma("unroll")                                                \
            for (int ks = 0; ks < 8; ++ks) {                                 \
                bf16x8 be = *(const bf16x8*)(rbase + ((8 * q + ks) ^ sw) * 16);\
                acc = __builtin_amdgcn_mfma_f32_16x16x32_bf16(bw[ks], be, acc, 0, 0, 0);\
            }                                                                \
            float part = Vv4[0] * fast_tanh(acc[0] + wd4[0])                 \
                       + Vv4[1] * fast_tanh(acc[1] + wd4[1])                 \
                       + Vv4[2] * fast_tanh(acc[2] + wd4[2])                 \
                       + Vv4[3] * fast_tanh(acc[3] + wd4[3]);                \
            part += __shfl_xor(part, 16, 64);                                \
            part += __shfl_xor(part, 32, 64);                                \
            if (lane < 16)                                                   \
                red[w][(HT) * 32 + g * 16 + lane] = part;                    \
        }                                                                    \
    }

#define BARRIER() asm volatile("s_waitcnt lgkmcnt(0)\n\ts_barrier" ::: "memory")

    for (int it = 0; it < 8; ++it) {
        const int ht0 = 2 * it;
        // even half-tile: xa -> buf0
        STAGE(xa, tile_lds[0]);
        if (it < 7) ISSUE(xa, ht0 + 2);
        BARRIER();
        COMPUTE(tile_lds[0], ht0);
        // odd half-tile: xb -> buf1
        STAGE(xb, tile_lds[1]);
        if (it < 7) ISSUE(xb, ht0 + 3);
        BARRIER();
        COMPUTE(tile_lds[1], ht0 + 1);
    }

#undef STAGE
#undef ISSUE
#undef COMPUTE
#undef BARRIER

    __syncthreads();
    // ---- combine 8 wave-partials for all 512 rows, coalesced store ----
    float s = 0.f;
    #pragma unroll
    for (int ww = 0; ww < 8; ++ww) s += red[ww][tid];
    out[(size_t)b * T_ + t0 + tid] = s;
}

extern "C" void kernel_launch(void* const* d_in, const int* in_sizes, int n_in,
                              void* d_out, int out_size, void* d_ws, size_t ws_size,
                              hipStream_t stream) {
    const float* enc = (const float*)d_in[0];
    const float* dec = (const float*)d_in[1];
    const float* W1  = (const float*)d_in[2];
    const float* W2  = (const float*)d_in[3];
    const float* V   = (const float*)d_in[4];
    float* out = (float*)d_out;

    attn_fused<<<512, 512, 0, stream>>>(enc, dec, W1, W2, V, out);
}